// Round 6
// baseline (1185.459 us; speedup 1.0000x reference)
//
#include <hip/hip_runtime.h>

typedef __attribute__((ext_vector_type(4))) float f32x4;
typedef __attribute__((ext_vector_type(8))) _Float16 f16x8;

#define AS1 __attribute__((address_space(1)))
#define AS3 __attribute__((address_space(3)))

// async global->LDS, 16B per lane (dest = wave-uniform base + lane*16B)
__device__ __forceinline__ void async16(const void* g, void* l) {
  __builtin_amdgcn_global_load_lds((const AS1 void*)g, (AS3 void*)l, 16, 0, 0);
}

// Uniform cubic B-spline bases, closed form (C2 => ulp-level cell
// misassignment harmless; validated rounds 4->5: identical absmax).
__device__ __forceinline__ f16x8 expand_bases(float x) {
  const float t0 = (float)(-3) * 0.4f - 1.0f;
  float s = (x - t0) * 2.5f;
  bool in = (s >= 0.0f) && (s < 11.0f);
  int c = (int)s;
  c = c > 10 ? 10 : c;
  float u = s - (float)c;
  float um = 1.0f - u;
  float u2 = u * u, u3 = u2 * u;
  float w3 = in ? u3 * (1.0f / 6.0f) : 0.f;
  float w2 = in ? (1.0f + 3.0f * u + 3.0f * u2 - 3.0f * u3) * (1.0f / 6.0f) : 0.f;
  float w1 = in ? (4.0f - 6.0f * u2 + 3.0f * u3) * (1.0f / 6.0f) : 0.f;
  float w0 = in ? um * um * um * (1.0f / 6.0f) : 0.f;
  f16x8 r;
#pragma unroll
  for (int j = 0; j < 8; ++j) {
    int d = c - j;
    float w = (d == 0) ? w3 : (d == 1) ? w2 : (d == 2) ? w1 : (d == 3) ? w0 : 0.f;
    r[j] = (_Float16)w;
  }
  return r;
}

// gate_probs[b][e] = softmax_e( x[b,:] . gate_w[e,:] + gate_b[e] ), fp32
__global__ __launch_bounds__(256) void gate_kernel(const float* __restrict__ x,
                                                   const float* __restrict__ gw,
                                                   const float* __restrict__ gb,
                                                   float* __restrict__ gate) {
  const int b = blockIdx.x * 4 + (threadIdx.x >> 6);
  const int lane = threadIdx.x & 63;
  f32x4 x0 = *(const f32x4*)(x + ((size_t)b << 9) + lane * 8);
  f32x4 x1 = *(const f32x4*)(x + ((size_t)b << 9) + lane * 8 + 4);
  float lg[8];
#pragma unroll
  for (int e = 0; e < 8; ++e) {
    f32x4 w0 = *(const f32x4*)(gw + ((size_t)e << 9) + lane * 8);
    f32x4 w1 = *(const f32x4*)(gw + ((size_t)e << 9) + lane * 8 + 4);
    float d = 0.f;
#pragma unroll
    for (int j = 0; j < 4; ++j) d += x0[j] * w0[j] + x1[j] * w1[j];
#pragma unroll
    for (int m = 32; m >= 1; m >>= 1) d += __shfl_xor(d, m, 64);
    lg[e] = d + gb[e];
  }
  float mx = lg[0];
#pragma unroll
  for (int e = 1; e < 8; ++e) mx = fmaxf(mx, lg[e]);
  float p[8], ssum = 0.f;
#pragma unroll
  for (int e = 0; e < 8; ++e) { p[e] = __expf(lg[e] - mx); ssum += p[e]; }
  float mine = 0.f;
#pragma unroll
  for (int e = 0; e < 8; ++e) mine = (lane == e) ? p[e] / ssum : mine;
  if (lane < 8) gate[(size_t)b * 8 + lane] = mine;
}

// W'[row][k] (row = e*512+o, ld=4608), fp16
__global__ __launch_bounds__(256) void prep_w_kernel(const float* __restrict__ bw,
                                                     const float* __restrict__ sw,
                                                     const float* __restrict__ sc,
                                                     _Float16* __restrict__ W) {
  size_t tid = (size_t)blockIdx.x * 256 + threadIdx.x;
  const size_t NSPL = (size_t)4096 * 512;
  if (tid < NSPL) {
    size_t row = tid >> 9;
    int i = (int)(tid & 511);
    float s = sc[(row << 9) + i];
    const float* sp = sw + (((row << 9) + (size_t)i) << 3);
    f32x4 v0 = *(const f32x4*)sp;
    f32x4 v1 = *(const f32x4*)(sp + 4);
    f16x8 o;
#pragma unroll
    for (int j = 0; j < 4; ++j) { o[j] = (_Float16)(v0[j] * s); o[4 + j] = (_Float16)(v1[j] * s); }
    *(f16x8*)(W + row * 4608 + 512 + (size_t)i * 8) = o;
  } else {
    size_t t2 = tid - NSPL;
    size_t row = t2 >> 6;
    int i8 = (int)((t2 & 63) << 3);
    const float* bp = bw + (row << 9) + i8;
    f32x4 v0 = *(const f32x4*)bp;
    f32x4 v1 = *(const f32x4*)(bp + 4);
    f16x8 o;
#pragma unroll
    for (int j = 0; j < 4; ++j) { o[j] = (_Float16)v0[j]; o[4 + j] = (_Float16)v1[j]; }
    *(f16x8*)(W + row * 4608 + i8) = o;
  }
}

// A1[r][k] fp16, full M: k<512 silu(x), else bases(x_i)[c]
__global__ __launch_bounds__(256) void expand_x_kernel(const float* __restrict__ x,
                                                       _Float16* __restrict__ A1) {
  const int tid = blockIdx.x * 256 + threadIdx.x;
  const int r = tid >> 9;
  const int i = tid & 511;
  const float xv = x[((size_t)r << 9) + i];
  const float s = xv / (1.0f + __expf(-xv));
  _Float16* drow = A1 + (size_t)r * 4608;
  drow[i] = (_Float16)s;
  *(f16x8*)(drow + 512 + (size_t)i * 8) = expand_bases(xv);
}

// Layer-1 GEMM (m97 structure): writes h fp16 [e][4096][512] row-major.
__global__ __launch_bounds__(256) void gemm_h(const _Float16* __restrict__ A1,
                                              const _Float16* __restrict__ W1,
                                              _Float16* __restrict__ h) {
  __shared__ _Float16 As[128 * 32];
  __shared__ _Float16 Bs[128 * 32];
  const int t = threadIdx.x;
  const int e = blockIdx.z;
  const int tileM = blockIdx.x * 128;
  const int tileN = blockIdx.y * 128;
  const _Float16* B = W1 + (size_t)e * 512 * 4608;

  const int srow = t >> 2;
  const int scol = (t & 3) * 8;
  const _Float16* gA0 = A1 + (size_t)(tileM + srow) * 4608 + scol;
  const _Float16* gA1 = A1 + (size_t)(tileM + 64 + srow) * 4608 + scol;
  const _Float16* gB0 = B + (size_t)(tileN + srow) * 4608 + scol;
  const _Float16* gB1 = B + (size_t)(tileN + 64 + srow) * 4608 + scol;
  _Float16* lA0 = &As[t * 8];
  _Float16* lA1 = &As[2048 + t * 8];
  _Float16* lB0 = &Bs[t * 8];
  _Float16* lB1 = &Bs[2048 + t * 8];

  const int lane = t & 63;
  const int wm = ((t >> 6) & 1) * 64;
  const int wn = ((t >> 6) >> 1) * 64;
  const int l16 = lane & 15;
  const int quad = lane >> 4;

  f32x4 acc[4][4];
#pragma unroll
  for (int i = 0; i < 4; ++i)
#pragma unroll
    for (int j = 0; j < 4; ++j) acc[i][j] = (f32x4){0.f, 0.f, 0.f, 0.f};

  for (int k0 = 0; k0 < 4608; k0 += 32) {
    async16(gA0 + k0, lA0);
    async16(gA1 + k0, lA1);
    async16(gB0 + k0, lB0);
    async16(gB1 + k0, lB1);
    __syncthreads();
    f16x8 af[4], bfr[4];
#pragma unroll
    for (int mt = 0; mt < 4; ++mt)
      af[mt] = *(const f16x8*)(&As[(wm + mt * 16 + l16) * 32 + quad * 8]);
#pragma unroll
    for (int nt = 0; nt < 4; ++nt)
      bfr[nt] = *(const f16x8*)(&Bs[(wn + nt * 16 + l16) * 32 + quad * 8]);
#pragma unroll
    for (int mt = 0; mt < 4; ++mt)
#pragma unroll
      for (int nt = 0; nt < 4; ++nt)
        acc[mt][nt] = __builtin_amdgcn_mfma_f32_16x16x32_f16(af[mt], bfr[nt], acc[mt][nt], 0, 0, 0);
    __syncthreads();
  }

  _Float16* hd = h + (size_t)e * 4096 * 512;
#pragma unroll
  for (int mt = 0; mt < 4; ++mt) {
#pragma unroll
    for (int r = 0; r < 4; ++r) {
      const int m = tileM + wm + mt * 16 + quad * 4 + r;
#pragma unroll
      for (int nt = 0; nt < 4; ++nt) {
        const int n = tileN + wn + nt * 16 + l16;
        hd[(size_t)m * 512 + n] = (_Float16)acc[mt][nt][r];
      }
    }
  }
}

// h[e][4096][512] -> hs = silu(h) (same layout) + h_T[e][512][4096]
// (LDS tile transpose: coalesced reads AND coalesced h_T writes).
__global__ __launch_bounds__(256) void fix_h(const _Float16* __restrict__ h,
                                             _Float16* __restrict__ hs,
                                             _Float16* __restrict__ h_T) {
  __shared__ _Float16 ldsT[64 * 72];  // [k][m], row stride 72 (16B-aligned rows)
  const int e = blockIdx.z;
  const int m0 = blockIdx.y * 64;
  const int k0 = blockIdx.x * 64;
  const _Float16* he = h + (size_t)e * 4096 * 512;
  _Float16* hse = hs + (size_t)e * 4096 * 512;
  _Float16* hTe = h_T + (size_t)e * 512 * 4096;
  const int t = threadIdx.x;
  const int r = t >> 3;          // 0..31 (m within tile)
  const int cg = (t & 7) * 8;    // k-group
#pragma unroll
  for (int half = 0; half < 2; ++half) {
    const int rr = r + half * 32;
    f16x8 v = *(const f16x8*)(he + (size_t)(m0 + rr) * 512 + k0 + cg);
    f16x8 s;
#pragma unroll
    for (int j = 0; j < 8; ++j) {
      float f = (float)v[j];
      s[j] = (_Float16)(f / (1.0f + __expf(-f)));
    }
    *(f16x8*)(hse + (size_t)(m0 + rr) * 512 + k0 + cg) = s;
#pragma unroll
    for (int j = 0; j < 8; ++j) ldsT[(cg + j) * 72 + rr] = v[j];
  }
  __syncthreads();
  const int kk = t >> 3;         // 0..31 (k within tile)
  const int mg = (t & 7) * 8;    // m-group
#pragma unroll
  for (int half = 0; half < 2; ++half) {
    const int kkk = kk + half * 32;
    f16x8 v = *(const f16x8*)(&ldsT[kkk * 72 + mg]);
    *(f16x8*)(hTe + (size_t)(k0 + kkk) * 4096 + m0 + mg) = v;
  }
}

// Layer-2 GEMM. k<512: As async-staged from hs (ld=512). k>=512: As built
// from h_T (coalesced 2B loads, lanes consecutive m) + closed-form bases,
// ds_write_b128 (2-way banks). Bs async from W2. Epilogue: fp32 atomics.
__global__ __launch_bounds__(256) void gemm_out(const _Float16* __restrict__ hs,
                                                const _Float16* __restrict__ h_T,
                                                const _Float16* __restrict__ W2,
                                                const float* __restrict__ gate,
                                                float* __restrict__ out) {
  __shared__ _Float16 As[128 * 32];
  __shared__ _Float16 Bs[128 * 32];
  const int t = threadIdx.x;
  const int e = blockIdx.z;
  const int tileM = blockIdx.x * 128;
  const int tileN = blockIdx.y * 128;
  const _Float16* hse = hs + (size_t)e * 4096 * 512;
  const _Float16* hTe = h_T + (size_t)e * 512 * 4096;
  const _Float16* B = W2 + (size_t)e * 512 * 4608;

  const int srow = t >> 2;
  const int scol = (t & 3) * 8;
  const _Float16* gA0 = hse + (size_t)(tileM + srow) * 512 + scol;
  const _Float16* gA1 = hse + (size_t)(tileM + 64 + srow) * 512 + scol;
  const _Float16* gB0 = B + (size_t)(tileN + srow) * 4608 + scol;
  const _Float16* gB1 = B + (size_t)(tileN + 64 + srow) * 4608 + scol;
  _Float16* lA0 = &As[t * 8];
  _Float16* lA1 = &As[2048 + t * 8];
  _Float16* lB0 = &Bs[t * 8];
  _Float16* lB1 = &Bs[2048 + t * 8];

  const int bm = t & 127;   // m within tile (A-build)
  const int bh = t >> 7;    // 0/1: covers i-offsets {bh, bh+2}

  const int lane = t & 63;
  const int wm = ((t >> 6) & 1) * 64;
  const int wn = ((t >> 6) >> 1) * 64;
  const int l16 = lane & 15;
  const int quad = lane >> 4;

  f32x4 acc[4][4];
#pragma unroll
  for (int i = 0; i < 4; ++i)
#pragma unroll
    for (int j = 0; j < 4; ++j) acc[i][j] = (f32x4){0.f, 0.f, 0.f, 0.f};

  // phase 1: silu region (k = 0..511), standard staged GEMM
  for (int k0 = 0; k0 < 512; k0 += 32) {
    async16(gA0 + k0, lA0);
    async16(gA1 + k0, lA1);
    async16(gB0 + k0, lB0);
    async16(gB1 + k0, lB1);
    __syncthreads();
    f16x8 af[4], bfr[4];
#pragma unroll
    for (int mt = 0; mt < 4; ++mt)
      af[mt] = *(const f16x8*)(&As[(wm + mt * 16 + l16) * 32 + quad * 8]);
#pragma unroll
    for (int nt = 0; nt < 4; ++nt)
      bfr[nt] = *(const f16x8*)(&Bs[(wn + nt * 16 + l16) * 32 + quad * 8]);
#pragma unroll
    for (int mt = 0; mt < 4; ++mt)
#pragma unroll
      for (int nt = 0; nt < 4; ++nt)
        acc[mt][nt] = __builtin_amdgcn_mfma_f32_16x16x32_f16(af[mt], bfr[nt], acc[mt][nt], 0, 0, 0);
    __syncthreads();
  }

  // phase 2: spline region (k = 512..4607), A built from h_T
  for (int k0 = 512; k0 < 4608; k0 += 32) {
    async16(gB0 + k0, lB0);
    async16(gB1 + k0, lB1);
    const int i0 = (k0 - 512) >> 3;
    const float vA = (float)hTe[(size_t)(i0 + bh) * 4096 + tileM + bm];
    const float vB = (float)hTe[(size_t)(i0 + 2 + bh) * 4096 + tileM + bm];
    f16x8 eA = expand_bases(vA);
    f16x8 eB = expand_bases(vB);
    *(f16x8*)&As[bm * 32 + bh * 8] = eA;
    *(f16x8*)&As[bm * 32 + (2 + bh) * 8] = eB;
    __syncthreads();
    f16x8 af[4], bfr[4];
#pragma unroll
    for (int mt = 0; mt < 4; ++mt)
      af[mt] = *(const f16x8*)(&As[(wm + mt * 16 + l16) * 32 + quad * 8]);
#pragma unroll
    for (int nt = 0; nt < 4; ++nt)
      bfr[nt] = *(const f16x8*)(&Bs[(wn + nt * 16 + l16) * 32 + quad * 8]);
#pragma unroll
    for (int mt = 0; mt < 4; ++mt)
#pragma unroll
      for (int nt = 0; nt < 4; ++nt)
        acc[mt][nt] = __builtin_amdgcn_mfma_f32_16x16x32_f16(af[mt], bfr[nt], acc[mt][nt], 0, 0, 0);
    __syncthreads();
  }

#pragma unroll
  for (int mt = 0; mt < 4; ++mt) {
#pragma unroll
    for (int r = 0; r < 4; ++r) {
      const int m = tileM + wm + mt * 16 + quad * 4 + r;
      const float gp = gate[(size_t)m * 8 + e];
      float* orow = out + (size_t)m * 512;
#pragma unroll
      for (int nt = 0; nt < 4; ++nt) {
        const int n = tileN + wn + nt * 16 + l16;
        atomicAdd(orow + n, gp * acc[mt][nt][r]);
      }
    }
  }
}

extern "C" void kernel_launch(void* const* d_in, const int* in_sizes, int n_in,
                              void* d_out, int out_size, void* d_ws, size_t ws_size,
                              hipStream_t stream) {
  (void)in_sizes; (void)n_in; (void)out_size; (void)ws_size;
  const float* x   = (const float*)d_in[0];
  const float* gw  = (const float*)d_in[1];
  const float* gb  = (const float*)d_in[2];
  const float* bw1 = (const float*)d_in[3];
  const float* sw1 = (const float*)d_in[4];
  const float* sc1 = (const float*)d_in[5];
  const float* bw2 = (const float*)d_in[6];
  const float* sw2 = (const float*)d_in[7];
  const float* sc2 = (const float*)d_in[8];
  float* out = (float*)d_out;

  auto al = [](size_t v) { return (v + 255) & ~(size_t)255; };
  const size_t GATE_B = (size_t)4096 * 8 * 4;
  const size_t W_B    = (size_t)8 * 512 * 4608 * 2;   // 37.7 MB
  const size_t A1_B   = (size_t)4096 * 4608 * 2;      // 37.7 MB
  const size_t H_B    = (size_t)8 * 4096 * 512 * 2;   // 33.5 MB
  // total ~214 MB (ws >= ~245 MB per round-3 evidence)

  char* p = (char*)d_ws;
  float* gate    = (float*)p; p += al(GATE_B);
  _Float16* W1   = (_Float16*)p; p += al(W_B);
  _Float16* W2   = (_Float16*)p; p += al(W_B);
  _Float16* A1   = (_Float16*)p; p += al(A1_B);
  _Float16* hbuf = (_Float16*)p; p += al(H_B);
  _Float16* hsb  = (_Float16*)p; p += al(H_B);
  _Float16* hTb  = (_Float16*)p;

  hipMemsetAsync(out, 0, (size_t)4096 * 512 * 4, stream);
  gate_kernel<<<1024, 256, 0, stream>>>(x, gw, gb, gate);
  prep_w_kernel<<<9216, 256, 0, stream>>>(bw1, sw1, sc1, W1);
  prep_w_kernel<<<9216, 256, 0, stream>>>(bw2, sw2, sc2, W2);
  expand_x_kernel<<<8192, 256, 0, stream>>>(x, A1);

  dim3 grid(32, 4, 8);
  gemm_h<<<grid, 256, 0, stream>>>(A1, W1, hbuf);
  fix_h<<<dim3(8, 64, 8), 256, 0, stream>>>(hbuf, hsb, hTb);
  gemm_out<<<grid, 256, 0, stream>>>(hsb, hTb, W2, gate, out);
}

// Round 7
// 945.616 us; speedup vs baseline: 1.2536x; 1.2536x over previous
//
#include <hip/hip_runtime.h>

typedef __attribute__((ext_vector_type(4))) float f32x4;
typedef __attribute__((ext_vector_type(8))) _Float16 f16x8;

#define AS1 __attribute__((address_space(1)))
#define AS3 __attribute__((address_space(3)))

// async global->LDS, 16B per lane (dest = wave-uniform base + lane*16B)
__device__ __forceinline__ void async16(const void* g, void* l) {
  __builtin_amdgcn_global_load_lds((const AS1 void*)g, (AS3 void*)l, 16, 0, 0);
}

// Uniform cubic B-spline bases, closed form (C2 => ulp-level cell
// misassignment harmless; validated rounds 4..6: absmax 0.03125 stable).
__device__ __forceinline__ f16x8 expand_bases(float x) {
  const float t0 = (float)(-3) * 0.4f - 1.0f;
  float s = (x - t0) * 2.5f;
  bool in = (s >= 0.0f) && (s < 11.0f);
  int c = (int)s;
  c = c > 10 ? 10 : c;
  float u = s - (float)c;
  float um = 1.0f - u;
  float u2 = u * u, u3 = u2 * u;
  float w3 = in ? u3 * (1.0f / 6.0f) : 0.f;
  float w2 = in ? (1.0f + 3.0f * u + 3.0f * u2 - 3.0f * u3) * (1.0f / 6.0f) : 0.f;
  float w1 = in ? (4.0f - 6.0f * u2 + 3.0f * u3) * (1.0f / 6.0f) : 0.f;
  float w0 = in ? um * um * um * (1.0f / 6.0f) : 0.f;
  f16x8 r;
#pragma unroll
  for (int j = 0; j < 8; ++j) {
    int d = c - j;
    float w = (d == 0) ? w3 : (d == 1) ? w2 : (d == 2) ? w1 : (d == 3) ? w0 : 0.f;
    r[j] = (_Float16)w;
  }
  return r;
}

__device__ __forceinline__ _Float16 silu16(_Float16 v) {
  float f = (float)v;
  return (_Float16)(f / (1.0f + __expf(-f)));
}

// gate_probs[b][e] = softmax_e( x[b,:] . gate_w[e,:] + gate_b[e] ), fp32
__global__ __launch_bounds__(256) void gate_kernel(const float* __restrict__ x,
                                                   const float* __restrict__ gw,
                                                   const float* __restrict__ gb,
                                                   float* __restrict__ gate) {
  const int b = blockIdx.x * 4 + (threadIdx.x >> 6);
  const int lane = threadIdx.x & 63;
  f32x4 x0 = *(const f32x4*)(x + ((size_t)b << 9) + lane * 8);
  f32x4 x1 = *(const f32x4*)(x + ((size_t)b << 9) + lane * 8 + 4);
  float lg[8];
#pragma unroll
  for (int e = 0; e < 8; ++e) {
    f32x4 w0 = *(const f32x4*)(gw + ((size_t)e << 9) + lane * 8);
    f32x4 w1 = *(const f32x4*)(gw + ((size_t)e << 9) + lane * 8 + 4);
    float d = 0.f;
#pragma unroll
    for (int j = 0; j < 4; ++j) d += x0[j] * w0[j] + x1[j] * w1[j];
#pragma unroll
    for (int m = 32; m >= 1; m >>= 1) d += __shfl_xor(d, m, 64);
    lg[e] = d + gb[e];
  }
  float mx = lg[0];
#pragma unroll
  for (int e = 1; e < 8; ++e) mx = fmaxf(mx, lg[e]);
  float p[8], ssum = 0.f;
#pragma unroll
  for (int e = 0; e < 8; ++e) { p[e] = __expf(lg[e] - mx); ssum += p[e]; }
  float mine = 0.f;
#pragma unroll
  for (int e = 0; e < 8; ++e) mine = (lane == e) ? p[e] / ssum : mine;
  if (lane < 8) gate[(size_t)b * 8 + lane] = mine;
}

// W'[row][k] (row = e*512+o, ld=4608), fp16
__global__ __launch_bounds__(256) void prep_w_kernel(const float* __restrict__ bw,
                                                     const float* __restrict__ sw,
                                                     const float* __restrict__ sc,
                                                     _Float16* __restrict__ W) {
  size_t tid = (size_t)blockIdx.x * 256 + threadIdx.x;
  const size_t NSPL = (size_t)4096 * 512;
  if (tid < NSPL) {
    size_t row = tid >> 9;
    int i = (int)(tid & 511);
    float s = sc[(row << 9) + i];
    const float* sp = sw + (((row << 9) + (size_t)i) << 3);
    f32x4 v0 = *(const f32x4*)sp;
    f32x4 v1 = *(const f32x4*)(sp + 4);
    f16x8 o;
#pragma unroll
    for (int j = 0; j < 4; ++j) { o[j] = (_Float16)(v0[j] * s); o[4 + j] = (_Float16)(v1[j] * s); }
    *(f16x8*)(W + row * 4608 + 512 + (size_t)i * 8) = o;
  } else {
    size_t t2 = tid - NSPL;
    size_t row = t2 >> 6;
    int i8 = (int)((t2 & 63) << 3);
    const float* bp = bw + (row << 9) + i8;
    f32x4 v0 = *(const f32x4*)bp;
    f32x4 v1 = *(const f32x4*)(bp + 4);
    f16x8 o;
#pragma unroll
    for (int j = 0; j < 4; ++j) { o[j] = (_Float16)v0[j]; o[4 + j] = (_Float16)v1[j]; }
    *(f16x8*)(W + row * 4608 + i8) = o;
  }
}

// A1[r][k] fp16, full M: k<512 silu(x), else bases(x_i)[c]
__global__ __launch_bounds__(256) void expand_x_kernel(const float* __restrict__ x,
                                                       _Float16* __restrict__ A1) {
  const int tid = blockIdx.x * 256 + threadIdx.x;
  const int r = tid >> 9;
  const int i = tid & 511;
  const float xv = x[((size_t)r << 9) + i];
  const float s = xv / (1.0f + __expf(-xv));
  _Float16* drow = A1 + (size_t)r * 4608;
  drow[i] = (_Float16)s;
  *(f16x8*)(drow + 512 + (size_t)i * 8) = expand_bases(xv);
}

// Layer-1 GEMM (m97 structure), grid (e=8, mtile=32, ntile=4): linear-id %8
// = expert -> each XCD works one expert (W1 slab L2-resident).
// Writes h fp16 [e][4096][512] row-major.
__global__ __launch_bounds__(256) void gemm_h(const _Float16* __restrict__ A1,
                                              const _Float16* __restrict__ W1,
                                              _Float16* __restrict__ h) {
  __shared__ _Float16 As[128 * 32];
  __shared__ _Float16 Bs[128 * 32];
  const int t = threadIdx.x;
  const int e = blockIdx.x;
  const int tileM = blockIdx.y * 128;
  const int tileN = blockIdx.z * 128;
  const _Float16* B = W1 + (size_t)e * 512 * 4608;

  const int srow = t >> 2;
  const int scol = (t & 3) * 8;
  const _Float16* gA0 = A1 + (size_t)(tileM + srow) * 4608 + scol;
  const _Float16* gA1 = A1 + (size_t)(tileM + 64 + srow) * 4608 + scol;
  const _Float16* gB0 = B + (size_t)(tileN + srow) * 4608 + scol;
  const _Float16* gB1 = B + (size_t)(tileN + 64 + srow) * 4608 + scol;
  _Float16* lA0 = &As[t * 8];
  _Float16* lA1 = &As[2048 + t * 8];
  _Float16* lB0 = &Bs[t * 8];
  _Float16* lB1 = &Bs[2048 + t * 8];

  const int lane = t & 63;
  const int wm = ((t >> 6) & 1) * 64;
  const int wn = ((t >> 6) >> 1) * 64;
  const int l16 = lane & 15;
  const int quad = lane >> 4;

  f32x4 acc[4][4];
#pragma unroll
  for (int i = 0; i < 4; ++i)
#pragma unroll
    for (int j = 0; j < 4; ++j) acc[i][j] = (f32x4){0.f, 0.f, 0.f, 0.f};

  for (int k0 = 0; k0 < 4608; k0 += 32) {
    async16(gA0 + k0, lA0);
    async16(gA1 + k0, lA1);
    async16(gB0 + k0, lB0);
    async16(gB1 + k0, lB1);
    __syncthreads();
    f16x8 af[4], bfr[4];
#pragma unroll
    for (int mt = 0; mt < 4; ++mt)
      af[mt] = *(const f16x8*)(&As[(wm + mt * 16 + l16) * 32 + quad * 8]);
#pragma unroll
    for (int nt = 0; nt < 4; ++nt)
      bfr[nt] = *(const f16x8*)(&Bs[(wn + nt * 16 + l16) * 32 + quad * 8]);
#pragma unroll
    for (int mt = 0; mt < 4; ++mt)
#pragma unroll
      for (int nt = 0; nt < 4; ++nt)
        acc[mt][nt] = __builtin_amdgcn_mfma_f32_16x16x32_f16(af[mt], bfr[nt], acc[mt][nt], 0, 0, 0);
    __syncthreads();
  }

  _Float16* hd = h + (size_t)e * 4096 * 512;
#pragma unroll
  for (int mt = 0; mt < 4; ++mt) {
#pragma unroll
    for (int r = 0; r < 4; ++r) {
      const int m = tileM + wm + mt * 16 + quad * 4 + r;
#pragma unroll
      for (int nt = 0; nt < 4; ++nt) {
        const int n = tileN + wn + nt * 16 + l16;
        hd[(size_t)m * 512 + n] = (_Float16)acc[mt][nt][r];
      }
    }
  }
}

// h[e][4096][512] -> h_T[e][512][4096] (LDS tile transpose, both sides coalesced)
__global__ __launch_bounds__(256) void fix_h(const _Float16* __restrict__ h,
                                             _Float16* __restrict__ h_T) {
  __shared__ _Float16 ldsT[64 * 72];
  const int e = blockIdx.z;
  const int m0 = blockIdx.y * 64;
  const int k0 = blockIdx.x * 64;
  const _Float16* he = h + (size_t)e * 4096 * 512;
  _Float16* hTe = h_T + (size_t)e * 512 * 4096;
  const int t = threadIdx.x;
  const int r = t >> 3;
  const int cg = (t & 7) * 8;
#pragma unroll
  for (int half = 0; half < 2; ++half) {
    const int rr = r + half * 32;
    f16x8 v = *(const f16x8*)(he + (size_t)(m0 + rr) * 512 + k0 + cg);
#pragma unroll
    for (int j = 0; j < 8; ++j) ldsT[(cg + j) * 72 + rr] = v[j];
  }
  __syncthreads();
  const int kk = t >> 3;
  const int mg = (t & 7) * 8;
#pragma unroll
  for (int half = 0; half < 2; ++half) {
    const int kkk = kk + half * 32;
    f16x8 v = *(const f16x8*)(&ldsT[kkk * 72 + mg]);
    *(f16x8*)(hTe + (size_t)(k0 + kkk) * 4096 + m0 + mg) = v;
  }
}

// Layer-2 GEMM, single-barrier double-buffered K-loop (144 BK=32 steps).
// kt<16: As built in-loop as silu(h) (coalesced row-major h reads).
// kt>=16: As built from prefetched h_T values + closed-form bases.
// Bs async-DMA double-buffered from W2. As row stride 40 => all ds ops at
// structural-minimum banking. Grid (e=8, m=32, n=4) => expert-per-XCD.
__global__ __launch_bounds__(256) void gemm_out(const _Float16* __restrict__ h,
                                                const _Float16* __restrict__ h_T,
                                                const _Float16* __restrict__ W2,
                                                const float* __restrict__ gate,
                                                float* __restrict__ out) {
  __shared__ _Float16 As[2][128 * 40];
  __shared__ _Float16 Bs[2][128 * 32];
  const int t = threadIdx.x;
  const int e = blockIdx.x;
  const int tileM = blockIdx.y * 128;
  const int tileN = blockIdx.z * 128;
  const _Float16* he  = h   + (size_t)e * 4096 * 512;
  const _Float16* hTe = h_T + (size_t)e * 512 * 4096;
  const _Float16* B   = W2  + (size_t)e * 512 * 4608;

  const int srow = t >> 2, scol = (t & 3) * 8;
  const _Float16* gB0 = B + (size_t)(tileN + srow) * 4608 + scol;
  const _Float16* gB1 = B + (size_t)(tileN + 64 + srow) * 4608 + scol;
  const _Float16* gH0 = he + (size_t)(tileM + srow) * 512 + scol;
  const _Float16* gH1 = he + (size_t)(tileM + 64 + srow) * 512 + scol;
  const int bm = t & 127, bh = t >> 7;
  const _Float16* hTm = hTe + tileM + bm;

  const int lane = t & 63;
  const int wm = ((t >> 6) & 1) * 64;
  const int wn = ((t >> 6) >> 1) * 64;
  const int l16 = lane & 15, quad = lane >> 4;

  f32x4 acc[4][4];
#pragma unroll
  for (int i = 0; i < 4; ++i)
#pragma unroll
    for (int j = 0; j < 4; ++j) acc[i][j] = (f32x4){0.f, 0.f, 0.f, 0.f};

  // prologue: stage kt=0 (silu region) into buffer 0
  async16(gB0, &Bs[0][t * 8]);
  async16(gB1, &Bs[0][2048 + t * 8]);
  {
    f16x8 h0 = *(const f16x8*)gH0;
    f16x8 h1 = *(const f16x8*)gH1;
    f16x8 s0, s1;
#pragma unroll
    for (int j = 0; j < 8; ++j) { s0[j] = silu16(h0[j]); s1[j] = silu16(h1[j]); }
    *(f16x8*)&As[0][srow * 40 + scol] = s0;
    *(f16x8*)&As[0][(64 + srow) * 40 + scol] = s1;
  }
  __syncthreads();

  for (int kt = 0; kt < 144; ++kt) {
    const int cb = kt & 1, nb = cb ^ 1;
    const int nxt = kt + 1;
    const bool have = nxt < 144;
    f16x8 pv0, pv1;
    if (have) {
      async16(gB0 + nxt * 32, &Bs[nb][t * 8]);
      async16(gB1 + nxt * 32, &Bs[nb][2048 + t * 8]);
      if (nxt < 16) {
        pv0 = *(const f16x8*)(gH0 + nxt * 32);
        pv1 = *(const f16x8*)(gH1 + nxt * 32);
      } else {
        const int i0 = (nxt - 16) * 4;
        pv0[0] = hTm[(size_t)(i0 + bh) * 4096];
        pv1[0] = hTm[(size_t)(i0 + 2 + bh) * 4096];
      }
    }
    // MFMA on current buffer
    f16x8 af[4], bfr[4];
#pragma unroll
    for (int mt = 0; mt < 4; ++mt)
      af[mt] = *(const f16x8*)(&As[cb][(wm + mt * 16 + l16) * 40 + quad * 8]);
#pragma unroll
    for (int nt = 0; nt < 4; ++nt)
      bfr[nt] = *(const f16x8*)(&Bs[cb][(wn + nt * 16 + l16) * 32 + quad * 8]);
#pragma unroll
    for (int mt = 0; mt < 4; ++mt)
#pragma unroll
      for (int nt = 0; nt < 4; ++nt)
        acc[mt][nt] = __builtin_amdgcn_mfma_f32_16x16x32_f16(af[mt], bfr[nt], acc[mt][nt], 0, 0, 0);
    // build next A tile into the other buffer
    if (have) {
      if (nxt < 16) {
        f16x8 s0, s1;
#pragma unroll
        for (int j = 0; j < 8; ++j) { s0[j] = silu16(pv0[j]); s1[j] = silu16(pv1[j]); }
        *(f16x8*)&As[nb][srow * 40 + scol] = s0;
        *(f16x8*)&As[nb][(64 + srow) * 40 + scol] = s1;
      } else {
        f16x8 eA = expand_bases((float)pv0[0]);
        f16x8 eB = expand_bases((float)pv1[0]);
        *(f16x8*)&As[nb][bm * 40 + bh * 8] = eA;
        *(f16x8*)&As[nb][bm * 40 + (2 + bh) * 8] = eB;
      }
    }
    __syncthreads();  // protects As[nb] writes + drains Bs[nb] DMA
  }

#pragma unroll
  for (int mt = 0; mt < 4; ++mt) {
#pragma unroll
    for (int r = 0; r < 4; ++r) {
      const int m = tileM + wm + mt * 16 + quad * 4 + r;
      const float gp = gate[(size_t)m * 8 + e];
      float* orow = out + (size_t)m * 512;
#pragma unroll
      for (int nt = 0; nt < 4; ++nt) {
        const int n = tileN + wn + nt * 16 + l16;
        atomicAdd(orow + n, gp * acc[mt][nt][r]);
      }
    }
  }
}

extern "C" void kernel_launch(void* const* d_in, const int* in_sizes, int n_in,
                              void* d_out, int out_size, void* d_ws, size_t ws_size,
                              hipStream_t stream) {
  (void)in_sizes; (void)n_in; (void)out_size; (void)ws_size;
  const float* x   = (const float*)d_in[0];
  const float* gw  = (const float*)d_in[1];
  const float* gb  = (const float*)d_in[2];
  const float* bw1 = (const float*)d_in[3];
  const float* sw1 = (const float*)d_in[4];
  const float* sc1 = (const float*)d_in[5];
  const float* bw2 = (const float*)d_in[6];
  const float* sw2 = (const float*)d_in[7];
  const float* sc2 = (const float*)d_in[8];
  float* out = (float*)d_out;

  auto al = [](size_t v) { return (v + 255) & ~(size_t)255; };
  const size_t GATE_B = (size_t)4096 * 8 * 4;
  const size_t W_B    = (size_t)8 * 512 * 4608 * 2;   // 37.7 MB
  const size_t A1_B   = (size_t)4096 * 4608 * 2;      // 37.7 MB
  const size_t H_B    = (size_t)8 * 4096 * 512 * 2;   // 33.5 MB
  // total ~180 MB (ws >= 245 MB per round-3 evidence)

  char* p = (char*)d_ws;
  float* gate    = (float*)p; p += al(GATE_B);
  _Float16* W1   = (_Float16*)p; p += al(W_B);
  _Float16* W2   = (_Float16*)p; p += al(W_B);
  _Float16* A1   = (_Float16*)p; p += al(A1_B);
  _Float16* hbuf = (_Float16*)p; p += al(H_B);
  _Float16* hTb  = (_Float16*)p;

  hipMemsetAsync(out, 0, (size_t)4096 * 512 * 4, stream);
  gate_kernel<<<1024, 256, 0, stream>>>(x, gw, gb, gate);
  prep_w_kernel<<<9216, 256, 0, stream>>>(bw1, sw1, sc1, W1);
  prep_w_kernel<<<9216, 256, 0, stream>>>(bw2, sw2, sc2, W2);
  expand_x_kernel<<<8192, 256, 0, stream>>>(x, A1);

  gemm_h<<<dim3(8, 32, 4), 256, 0, stream>>>(A1, W1, hbuf);
  fix_h<<<dim3(8, 64, 8), 256, 0, stream>>>(hbuf, hTb);
  gemm_out<<<dim3(8, 32, 4), 256, 0, stream>>>(hbuf, hTb, W2, gate, out);
}